// Round 3
// baseline (448.270 us; speedup 1.0000x reference)
//
#include <hip/hip_runtime.h>
#include <hip/hip_bf16.h>

#define NN 50000
#define EE 800000
#define IND 128
#define OUTD 64
#define NB 49           // ceil(NN/1024) scan blocks
#define PA_BLOCKS 782   // ceil(NN/64) GEMM blocks
#define DEG_BLOCKS 391  // ceil(EE/2048) deg blocks

// ---------------- Deg: count in-degree (CSR sizing) ------------------------
__global__ __launch_bounds__(256) void k_deg(
    const int* __restrict__ edst, int* __restrict__ deg) {
  const int base = blockIdx.x * 2048 + threadIdx.x;
#pragma unroll
  for (int j = 0; j < 8; ++j) {
    int e = base + j * 256;
    if (e < EE) atomicAdd(&deg[edst[e]], 1);
  }
}

// ---------------- GEMM: z = h@W_fc^T, s1 = z.w1, s2 = z.w2 -----------------
// lane l owns output col l; W[l][:] in 128 VGPRs (LDS-staged); h row
// broadcast via v_readlane; 4 accumulator chains for FMA-latency ILP.
// (256,2): VGPR budget 256 -> Wreg[128] stays in registers (needs ~180),
// 2 waves/SIMD for latency hiding. (R1 post-mortem: default heuristic gave
// 80 VGPR -> Wreg spilled to scratch -> that was k_front's 126 us.)
__global__ __launch_bounds__(256, 2) void k_gemm(
    const float* __restrict__ h, const float* __restrict__ W,
    const float* __restrict__ attn, __hip_bfloat16* __restrict__ zb,
    float* __restrict__ s1, float* __restrict__ s2) {
  const int tid = threadIdx.x;
  __shared__ float Wl[64 * 129];
#pragma unroll
  for (int j = 0; j < 8; ++j) {
    int i4 = tid + j * 256;
    const float4 v = reinterpret_cast<const float4*>(W)[i4];
    int i = i4 * 4;
    int col = i >> 7, k = i & 127;
    float* p = &Wl[col * 129 + k];
    p[0] = v.x; p[1] = v.y; p[2] = v.z; p[3] = v.w;
  }
  __syncthreads();
  const int lane = tid & 63;
  const int wid = tid >> 6;
  float Wreg[128];
#pragma unroll
  for (int k = 0; k < 128; ++k) Wreg[k] = Wl[lane * 129 + k];
  const float w1v = attn[lane];
  const float w2v = attn[64 + lane];
  const int base = blockIdx.x * 64 + wid * 16;
  int rmax = NN - base;
  rmax = rmax > 16 ? 16 : (rmax < 0 ? 0 : rmax);
  for (int i = 0; i < rmax; ++i) {
    int r = base + i;
    const float* hr = h + (size_t)r * IND;
    float h0 = hr[lane];
    float h1 = hr[64 + lane];
    float a0 = 0.f, a1 = 0.f, a2 = 0.f, a3 = 0.f;
#pragma unroll
    for (int k = 0; k < 16; ++k) {
      a0 = fmaf(__uint_as_float(__builtin_amdgcn_readlane(__float_as_uint(h0), 4 * k)),     Wreg[4 * k], a0);
      a1 = fmaf(__uint_as_float(__builtin_amdgcn_readlane(__float_as_uint(h0), 4 * k + 1)), Wreg[4 * k + 1], a1);
      a2 = fmaf(__uint_as_float(__builtin_amdgcn_readlane(__float_as_uint(h0), 4 * k + 2)), Wreg[4 * k + 2], a2);
      a3 = fmaf(__uint_as_float(__builtin_amdgcn_readlane(__float_as_uint(h0), 4 * k + 3)), Wreg[4 * k + 3], a3);
    }
#pragma unroll
    for (int k = 0; k < 16; ++k) {
      a0 = fmaf(__uint_as_float(__builtin_amdgcn_readlane(__float_as_uint(h1), 4 * k)),     Wreg[64 + 4 * k], a0);
      a1 = fmaf(__uint_as_float(__builtin_amdgcn_readlane(__float_as_uint(h1), 4 * k + 1)), Wreg[64 + 4 * k + 1], a1);
      a2 = fmaf(__uint_as_float(__builtin_amdgcn_readlane(__float_as_uint(h1), 4 * k + 2)), Wreg[64 + 4 * k + 2], a2);
      a3 = fmaf(__uint_as_float(__builtin_amdgcn_readlane(__float_as_uint(h1), 4 * k + 3)), Wreg[64 + 4 * k + 3], a3);
    }
    float acc = (a0 + a1) + (a2 + a3);
    zb[(size_t)r * OUTD + lane] = __float2bfloat16(acc);
    float p = acc * w1v, q = acc * w2v;
#pragma unroll
    for (int m = 32; m >= 1; m >>= 1) {
      p += __shfl_xor(p, m, 64);
      q += __shfl_xor(q, m, 64);
    }
    if (lane == 0) { s1[r] = p; s2[r] = q; }
  }
}

// ---------------- Scan: exclusive prefix over deg (CSR offsets) ------------
__global__ __launch_bounds__(1024) void k_scan1(
    const int* __restrict__ deg, int* __restrict__ offL,
    int* __restrict__ blocksum) {
  __shared__ int wsum[16];
  __shared__ int woff[17];
  const int tid = threadIdx.x;
  const int gid = blockIdx.x * 1024 + tid;
  const int lane = tid & 63, wid = tid >> 6;
  int v = (gid < NN) ? deg[gid] : 0;
  int incl = v;
#pragma unroll
  for (int o = 1; o < 64; o <<= 1) {
    int t = __shfl_up(incl, o, 64);
    if (lane >= o) incl += t;
  }
  if (lane == 63) wsum[wid] = incl;
  __syncthreads();
  if (wid == 0 && lane < 16) {
    int s = wsum[lane];
    int si = s;
#pragma unroll
    for (int o = 1; o < 16; o <<= 1) {
      int t = __shfl_up(si, o, 64);
      if (lane >= o) si += t;
    }
    woff[lane] = si - s;
    if (lane == 15) woff[16] = si;
  }
  __syncthreads();
  if (gid < NN) offL[gid] = woff[wid] + incl - v;
  if (tid == 0) blocksum[blockIdx.x] = woff[16];
}

__global__ __launch_bounds__(64) void k_scan2(
    const int* __restrict__ blocksum, int* __restrict__ blockoff) {
  const int lane = threadIdx.x;
  int v = (lane < NB) ? blocksum[lane] : 0;
  int incl = v;
#pragma unroll
  for (int o = 1; o < 64; o <<= 1) {
    int t = __shfl_up(incl, o, 64);
    if (lane >= o) incl += t;
  }
  if (lane < NB) blockoff[lane] = incl - v;
}

// ---------------- Scatter (fused r_h·w3): 16-lane group per 4 edges --------
// Group g handles edges e0..e0+3. The 16 lanes read r_h rows as 16 x float4
// (coalesced 256 B per row), dot with w3 in-register, 4 shfl_xor rounds
// reduce within the group. Lane sub==0 then finishes the 4 edges:
// ee = exp(leaky(s1[src]+s2[dst]+d3)), slot = CSR offset + atomic cursor.
// This kernel now carries the full 204.8 MB r_h stream (was a separate
// k_stream stage + 6.4 MB d3 roundtrip + 6.4 MB rank roundtrip).
__global__ __launch_bounds__(256) void k_scatter(
    const int* __restrict__ esrc, const int* __restrict__ edst,
    const float* __restrict__ r_h, const float* __restrict__ attn,
    const float* __restrict__ s1, const float* __restrict__ s2,
    const int* __restrict__ offL, const int* __restrict__ blockoff,
    int* __restrict__ cur, int2* __restrict__ pairs) {
  const int tid = threadIdx.x;
  const int g = tid >> 4, sub = tid & 15;
  const int e0 = blockIdx.x * 64 + g * 4;  // grid exact: 12500*64 = 800000
  const float4 wv = reinterpret_cast<const float4*>(attn + 2 * OUTD)[sub];
  float4 rv[4];
#pragma unroll
  for (int j = 0; j < 4; ++j)
    rv[j] = reinterpret_cast<const float4*>(r_h)[(size_t)(e0 + j) * 16 + sub];
  float d[4];
#pragma unroll
  for (int j = 0; j < 4; ++j)
    d[j] = rv[j].x * wv.x + rv[j].y * wv.y + rv[j].z * wv.z + rv[j].w * wv.w;
#pragma unroll
  for (int m = 1; m <= 8; m <<= 1) {  // masks 1,2,4,8 stay in 16-lane group
#pragma unroll
    for (int j = 0; j < 4; ++j) d[j] += __shfl_xor(d[j], m, 64);
  }
  if (sub == 0) {
    const int4 s4  = *reinterpret_cast<const int4*>(esrc + e0);
    const int4 dd4 = *reinterpret_cast<const int4*>(edst + e0);
    float v1x = s1[s4.x], v1y = s1[s4.y], v1z = s1[s4.z], v1w = s1[s4.w];
    float v2x = s2[dd4.x], v2y = s2[dd4.y], v2z = s2[dd4.z], v2w = s2[dd4.w];
    int oLx = offL[dd4.x], oLy = offL[dd4.y], oLz = offL[dd4.z], oLw = offL[dd4.w];
    int bx = blockoff[dd4.x >> 10], by = blockoff[dd4.y >> 10];
    int bz = blockoff[dd4.z >> 10], bw = blockoff[dd4.w >> 10];
    float ax = v1x + v2x + d[0], ay = v1y + v2y + d[1];
    float az = v1z + v2z + d[2], aw = v1w + v2w + d[3];
    float ex = __expf(ax > 0.f ? ax : 0.01f * ax);
    float ey = __expf(ay > 0.f ? ay : 0.01f * ay);
    float ez = __expf(az > 0.f ? az : 0.01f * az);
    float ew = __expf(aw > 0.f ? aw : 0.01f * aw);
    pairs[bx + oLx + atomicAdd(&cur[dd4.x], 1)] = make_int2(s4.x, __float_as_int(ex));
    pairs[by + oLy + atomicAdd(&cur[dd4.y], 1)] = make_int2(s4.y, __float_as_int(ey));
    pairs[bz + oLz + atomicAdd(&cur[dd4.z], 1)] = make_int2(s4.z, __float_as_int(ez));
    pairs[bw + oLw + atomicAdd(&cur[dd4.w], 1)] = make_int2(s4.w, __float_as_int(ew));
  }
}

// ---------------- Agg: gather per dst node ---------------------------------
// One wave per node. lane = (slot = lane>>4, sub = lane&15): slot indexes
// edges, sub the channel-quad. Gathers bf16 zb rows (128 B); 16 edges per
// mega-iteration -> 8 loads in flight/lane. Loop-weight epilogue also bf16.
__global__ __launch_bounds__(256) void k_agg(
    const __hip_bfloat16* __restrict__ zb, const int2* __restrict__ pairs,
    const int* __restrict__ offL, const int* __restrict__ blockoff,
    const int* __restrict__ deg, const float* __restrict__ LW,
    float* __restrict__ out) {
  const int lane = threadIdx.x & 63, wid = threadIdx.x >> 6;
  const int slot = lane >> 4, sub = lane & 15;
  float4 LWreg[16];  // LW[slot*16+kl][4*sub..4*sub+3]
#pragma unroll
  for (int kl = 0; kl < 16; ++kl)
    LWreg[kl] = reinterpret_cast<const float4*>(LW)[(slot * 16 + kl) * 16 + sub];
  const int r = blockIdx.x * 4 + wid;  // grid exact: 12500*4 = 50000
  const int cnt = deg[r];
  const int2* pp = pairs + (blockoff[r >> 10] + offL[r]);
  float4 acc = make_float4(0.f, 0.f, 0.f, 0.f);
  float wsum = 0.f;
  for (int i = 0; i < cnt; i += 16) {
    int2 p[4];
    float w[4];
#pragma unroll
    for (int j = 0; j < 4; ++j) {
      int e = i + j * 4 + slot;
      bool v = e < cnt;
      p[j] = pp[v ? e : 0];  // pp[0] valid: loop entered => cnt >= 1
      w[j] = v ? __int_as_float(p[j].y) : 0.f;
    }
#pragma unroll
    for (int j = 0; j < 4; ++j) {
      ushort4 uz = reinterpret_cast<const ushort4*>(zb)[(size_t)p[j].x * 16 + sub];
      acc.x = fmaf(w[j], __uint_as_float((unsigned)uz.x << 16), acc.x);
      acc.y = fmaf(w[j], __uint_as_float((unsigned)uz.y << 16), acc.y);
      acc.z = fmaf(w[j], __uint_as_float((unsigned)uz.z << 16), acc.z);
      acc.w = fmaf(w[j], __uint_as_float((unsigned)uz.w << 16), acc.w);
      wsum += w[j];
    }
  }
  // loop-weight partial: k in [slot*16, slot*16+16)
  float4 lacc = make_float4(0.f, 0.f, 0.f, 0.f);
#pragma unroll
  for (int j = 0; j < 4; ++j) {
    ushort4 uz = reinterpret_cast<const ushort4*>(zb)[(size_t)r * 16 + slot * 4 + j];
    float zk[4] = {__uint_as_float((unsigned)uz.x << 16),
                   __uint_as_float((unsigned)uz.y << 16),
                   __uint_as_float((unsigned)uz.z << 16),
                   __uint_as_float((unsigned)uz.w << 16)};
#pragma unroll
    for (int c = 0; c < 4; ++c) {
      float4 lw = LWreg[4 * j + c];
      lacc.x = fmaf(zk[c], lw.x, lacc.x);
      lacc.y = fmaf(zk[c], lw.y, lacc.y);
      lacc.z = fmaf(zk[c], lw.z, lacc.z);
      lacc.w = fmaf(zk[c], lw.w, lacc.w);
    }
  }
  wsum += __shfl_xor(wsum, 16, 64);
  wsum += __shfl_xor(wsum, 32, 64);
  float inv = (cnt > 0) ? 1.f / wsum : 0.f;
  float4 t;
  t.x = fmaf(acc.x, inv, lacc.x);
  t.y = fmaf(acc.y, inv, lacc.y);
  t.z = fmaf(acc.z, inv, lacc.z);
  t.w = fmaf(acc.w, inv, lacc.w);
  t.x += __shfl_xor(t.x, 16, 64); t.x += __shfl_xor(t.x, 32, 64);
  t.y += __shfl_xor(t.y, 16, 64); t.y += __shfl_xor(t.y, 32, 64);
  t.z += __shfl_xor(t.z, 16, 64); t.z += __shfl_xor(t.z, 32, 64);
  t.w += __shfl_xor(t.w, 16, 64); t.w += __shfl_xor(t.w, 32, 64);
  if (slot == 0) {
    float4 res;
    res.x = (cnt > 0 && t.x > 0.f) ? t.x : 0.f;
    res.y = (cnt > 0 && t.y > 0.f) ? t.y : 0.f;
    res.z = (cnt > 0 && t.z > 0.f) ? t.z : 0.f;
    res.w = (cnt > 0 && t.w > 0.f) ? t.w : 0.f;
    reinterpret_cast<float4*>(out)[(size_t)r * 16 + sub] = res;
  }
}

extern "C" void kernel_launch(void* const* d_in, const int* in_sizes, int n_in,
                              void* d_out, int out_size, void* d_ws, size_t ws_size,
                              hipStream_t stream) {
  const float* h    = (const float*)d_in[0];  // [N,128]
  const float* r_h  = (const float*)d_in[1];  // [E,64]
  const float* W_fc = (const float*)d_in[2];  // [64,128]
  const float* attn = (const float*)d_in[3];  // [1,192]
  const float* LW   = (const float*)d_in[4];  // [64,64]
  const int* esrc   = (const int*)d_in[5];    // [E]
  const int* edst   = (const int*)d_in[6];    // [E]
  float* out = (float*)d_out;                 // [N,64]

  char* ws = (char*)d_ws;
  __hip_bfloat16* zb = (__hip_bfloat16*)(ws);  //  6,400,000 B
  int2*  pairs = (int2*)(ws + 6400000);        //  6,400,000 B
  float* s1    = (float*)(ws + 12800000);      //    200,000 B
  float* s2    = (float*)(ws + 13000000);      //    200,000 B
  int*   deg   = (int*)(ws + 13200000);        //    200,000 B
  int*   cur   = (int*)(ws + 13400000);        //    200,000 B
  int*   offL  = (int*)(ws + 13600000);        //    200,000 B
  int*   bsum  = (int*)(ws + 13800000);        //        256 B
  int*   boff  = (int*)(ws + 13801024);        //        256 B
  // total ws use ~13.8 MB

  hipMemsetAsync(ws + 13200000, 0, 400000, stream);  // deg + cur

  k_deg<<<DEG_BLOCKS, 256, 0, stream>>>(edst, deg);
  k_gemm<<<PA_BLOCKS, 256, 0, stream>>>(h, W_fc, attn, zb, s1, s2);
  k_scan1<<<NB, 1024, 0, stream>>>(deg, offL, bsum);
  k_scan2<<<1, 64, 0, stream>>>(bsum, boff);
  k_scatter<<<EE / 64, 256, 0, stream>>>(
      esrc, edst, r_h, attn, s1, s2, offL, boff, cur, pairs);
  k_agg<<<NN / 4, 256, 0, stream>>>(zb, pairs, offL, boff, deg, LW, out);
}

// Round 4
// 424.634 us; speedup vs baseline: 1.0557x; 1.0557x over previous
//
#include <hip/hip_runtime.h>
#include <hip/hip_bf16.h>

#define NN 50000
#define EE 800000
#define IND 128
#define OUTD 64
#define NB 49           // ceil(NN/1024) scan blocks
#define PA_BLOCKS 782   // ceil(NN/64) GEMM blocks
#define DEG_BLOCKS 391  // ceil(EE/2048) deg blocks
#define RH_BLOCKS 6250  // EE*16/2048 r_h-stream blocks (8 float4 per thread)

// ---------------- Front (fused, 3 block ranges, spill-free) ----------------
// [0,782):        z = h@W_fc^T (bf16 out), s1 = z.w1, s2 = z.w2 (VALU-bound)
// [782,1173):     deg/rank: rank[e] = atomicAdd(&deg[edst[e]],1)
// [1173,7423):    d3[e] = r_h[e]·w3 (204.8 MB HBM stream, 8 float4/thread)
// Fusion overlaps the VALU-bound GEMM under the BW-bound stream (R1 idea);
// __launch_bounds__(256,1) gives the 512-VGPR budget so Wreg[128] stays in
// registers (R1's 80-VGPR spill was the 126 us, proven R1->R2).
__global__ __launch_bounds__(256, 1) void k_front(
    const float* __restrict__ h, const float* __restrict__ W,
    const float* __restrict__ attn, const int* __restrict__ edst,
    const float* __restrict__ r_h,
    __hip_bfloat16* __restrict__ zb, float* __restrict__ s1,
    float* __restrict__ s2, int* __restrict__ deg, int* __restrict__ rank,
    float* __restrict__ d3) {
  const int tid = threadIdx.x;
  if (blockIdx.x >= PA_BLOCKS + DEG_BLOCKS) {  // ---- r_h·w3 stream
    const int base4 = (blockIdx.x - (PA_BLOCKS + DEG_BLOCKS)) * 2048 + tid;
    const int sub = tid & 15;
    const float4 wv = reinterpret_cast<const float4*>(attn + 2 * OUTD)[sub];
    float4 rv[8];
#pragma unroll
    for (int j = 0; j < 8; ++j)
      rv[j] = reinterpret_cast<const float4*>(r_h)[base4 + j * 256];
    float d[8];
#pragma unroll
    for (int j = 0; j < 8; ++j)
      d[j] = rv[j].x * wv.x + rv[j].y * wv.y + rv[j].z * wv.z + rv[j].w * wv.w;
#pragma unroll
    for (int m = 1; m <= 8; m <<= 1) {
#pragma unroll
      for (int j = 0; j < 8; ++j) d[j] += __shfl_xor(d[j], m, 64);
    }
    if (sub == 0) {
      const int row0 = base4 >> 4;
#pragma unroll
      for (int j = 0; j < 8; ++j) d3[row0 + 16 * j] = d[j];
    }
    return;
  }
  if (blockIdx.x >= PA_BLOCKS) {  // ---- deg/rank
    const int base = (blockIdx.x - PA_BLOCKS) * 2048 + tid;
#pragma unroll
    for (int j = 0; j < 8; ++j) {
      int e = base + j * 256;
      if (e < EE) rank[e] = atomicAdd(&deg[edst[e]], 1);
    }
    return;
  }
  // ---- GEMM: lane l owns output col l; W[l][:] in 128 VGPRs (LDS-staged);
  // h row broadcast via v_readlane; 4 accumulator chains for FMA-latency ILP.
  __shared__ float Wl[64 * 129];
#pragma unroll
  for (int j = 0; j < 8; ++j) {
    int i4 = tid + j * 256;
    const float4 v = reinterpret_cast<const float4*>(W)[i4];
    int i = i4 * 4;
    int col = i >> 7, k = i & 127;
    float* p = &Wl[col * 129 + k];
    p[0] = v.x; p[1] = v.y; p[2] = v.z; p[3] = v.w;
  }
  __syncthreads();
  const int lane = tid & 63;
  const int wid = tid >> 6;
  float Wreg[128];
#pragma unroll
  for (int k = 0; k < 128; ++k) Wreg[k] = Wl[lane * 129 + k];
  const float w1v = attn[lane];
  const float w2v = attn[64 + lane];
  const int base = blockIdx.x * 64 + wid * 16;
  int rmax = NN - base;
  rmax = rmax > 16 ? 16 : (rmax < 0 ? 0 : rmax);
  for (int i = 0; i < rmax; ++i) {
    int r = base + i;
    const float* hr = h + (size_t)r * IND;
    float h0 = hr[lane];
    float h1 = hr[64 + lane];
    float a0 = 0.f, a1 = 0.f, a2 = 0.f, a3 = 0.f;
#pragma unroll
    for (int k = 0; k < 16; ++k) {
      a0 = fmaf(__uint_as_float(__builtin_amdgcn_readlane(__float_as_uint(h0), 4 * k)),     Wreg[4 * k], a0);
      a1 = fmaf(__uint_as_float(__builtin_amdgcn_readlane(__float_as_uint(h0), 4 * k + 1)), Wreg[4 * k + 1], a1);
      a2 = fmaf(__uint_as_float(__builtin_amdgcn_readlane(__float_as_uint(h0), 4 * k + 2)), Wreg[4 * k + 2], a2);
      a3 = fmaf(__uint_as_float(__builtin_amdgcn_readlane(__float_as_uint(h0), 4 * k + 3)), Wreg[4 * k + 3], a3);
    }
#pragma unroll
    for (int k = 0; k < 16; ++k) {
      a0 = fmaf(__uint_as_float(__builtin_amdgcn_readlane(__float_as_uint(h1), 4 * k)),     Wreg[64 + 4 * k], a0);
      a1 = fmaf(__uint_as_float(__builtin_amdgcn_readlane(__float_as_uint(h1), 4 * k + 1)), Wreg[64 + 4 * k + 1], a1);
      a2 = fmaf(__uint_as_float(__builtin_amdgcn_readlane(__float_as_uint(h1), 4 * k + 2)), Wreg[64 + 4 * k + 2], a2);
      a3 = fmaf(__uint_as_float(__builtin_amdgcn_readlane(__float_as_uint(h1), 4 * k + 3)), Wreg[64 + 4 * k + 3], a3);
    }
    float acc = (a0 + a1) + (a2 + a3);
    zb[(size_t)r * OUTD + lane] = __float2bfloat16(acc);
    float p = acc * w1v, q = acc * w2v;
#pragma unroll
    for (int m = 32; m >= 1; m >>= 1) {
      p += __shfl_xor(p, m, 64);
      q += __shfl_xor(q, m, 64);
    }
    if (lane == 0) { s1[r] = p; s2[r] = q; }
  }
}

// ---------------- Scan: exclusive prefix over deg (CSR offsets) ------------
// Per-1024 block local offsets + per-block sums; the 49-entry block-level
// prefix is recomputed inline by consumers (k_scan2 dispatch eliminated).
__global__ __launch_bounds__(1024) void k_scan1(
    const int* __restrict__ deg, int* __restrict__ offL,
    int* __restrict__ blocksum) {
  __shared__ int wsum[16];
  __shared__ int woff[17];
  const int tid = threadIdx.x;
  const int gid = blockIdx.x * 1024 + tid;
  const int lane = tid & 63, wid = tid >> 6;
  int v = (gid < NN) ? deg[gid] : 0;
  int incl = v;
#pragma unroll
  for (int o = 1; o < 64; o <<= 1) {
    int t = __shfl_up(incl, o, 64);
    if (lane >= o) incl += t;
  }
  if (lane == 63) wsum[wid] = incl;
  __syncthreads();
  if (wid == 0 && lane < 16) {
    int s = wsum[lane];
    int si = s;
#pragma unroll
    for (int o = 1; o < 16; o <<= 1) {
      int t = __shfl_up(si, o, 64);
      if (lane >= o) si += t;
    }
    woff[lane] = si - s;
    if (lane == 15) woff[16] = si;
  }
  __syncthreads();
  if (gid < NN) offL[gid] = woff[wid] + incl - v;
  if (tid == 0) blocksum[blockIdx.x] = woff[16];
}

// ---------------- Scatter: 4 edges/thread, vector edge loads ---------------
// ee = exp(leaky(s1[src]+s2[dst]+d3[e])); pairs[off[dst]+rank[e]] = (src,ee).
// First wave computes the 49-entry block-offset prefix into LDS (replaces
// k_scan2). 4 edges/thread: int4/float4 coalesced stream loads, 12 random
// L2-hot gathers in flight. No seg_max: |a| small, exp safe in f32.
__global__ __launch_bounds__(256) void k_scatter(
    const int* __restrict__ esrc, const int* __restrict__ edst,
    const float* __restrict__ d3, const float* __restrict__ s1,
    const float* __restrict__ s2, const int* __restrict__ rank,
    const int* __restrict__ offL, const int* __restrict__ bsum,
    int2* __restrict__ pairs) {
  __shared__ int boffs[NB];
  if (threadIdx.x < 64) {
    int l = threadIdx.x;
    int v = (l < NB) ? bsum[l] : 0;
    int incl = v;
#pragma unroll
    for (int o = 1; o < 64; o <<= 1) {
      int t = __shfl_up(incl, o, 64);
      if (l >= o) incl += t;
    }
    if (l < NB) boffs[l] = incl - v;
  }
  __syncthreads();
  const int t = blockIdx.x * 256 + threadIdx.x;
  if (t >= EE / 4) return;
  const int4 s4 = reinterpret_cast<const int4*>(esrc)[t];
  const int4 dd4 = reinterpret_cast<const int4*>(edst)[t];
  const float4 d34 = reinterpret_cast<const float4*>(d3)[t];
  const int4 rk4 = reinterpret_cast<const int4*>(rank)[t];
  float v1x = s1[s4.x], v1y = s1[s4.y], v1z = s1[s4.z], v1w = s1[s4.w];
  float v2x = s2[dd4.x], v2y = s2[dd4.y], v2z = s2[dd4.z], v2w = s2[dd4.w];
  int oLx = offL[dd4.x], oLy = offL[dd4.y], oLz = offL[dd4.z], oLw = offL[dd4.w];
  int bx = boffs[dd4.x >> 10], by = boffs[dd4.y >> 10];
  int bz = boffs[dd4.z >> 10], bw = boffs[dd4.w >> 10];
  float ax = v1x + v2x + d34.x, ay = v1y + v2y + d34.y;
  float az = v1z + v2z + d34.z, aw = v1w + v2w + d34.w;
  float ex = __expf(ax > 0.f ? ax : 0.01f * ax);
  float ey = __expf(ay > 0.f ? ay : 0.01f * ay);
  float ez = __expf(az > 0.f ? az : 0.01f * az);
  float ew = __expf(aw > 0.f ? aw : 0.01f * aw);
  pairs[bx + oLx + rk4.x] = make_int2(s4.x, __float_as_int(ex));
  pairs[by + oLy + rk4.y] = make_int2(s4.y, __float_as_int(ey));
  pairs[bz + oLz + rk4.z] = make_int2(s4.z, __float_as_int(ez));
  pairs[bw + oLw + rk4.w] = make_int2(s4.w, __float_as_int(ew));
}

// ---------------- Agg: gather per dst node ---------------------------------
// One wave per node. lane = (slot = lane>>4, sub = lane&15): slot indexes
// edges, sub the channel-quad. Gathers bf16 zb rows (128 B); 16 edges per
// mega-iteration. First wave computes boffs inline (replaces k_scan2).
__global__ __launch_bounds__(256) void k_agg(
    const __hip_bfloat16* __restrict__ zb, const int2* __restrict__ pairs,
    const int* __restrict__ offL, const int* __restrict__ bsum,
    const int* __restrict__ deg, const float* __restrict__ LW,
    float* __restrict__ out) {
  __shared__ int boffs[NB];
  if (threadIdx.x < 64) {
    int l = threadIdx.x;
    int v = (l < NB) ? bsum[l] : 0;
    int incl = v;
#pragma unroll
    for (int o = 1; o < 64; o <<= 1) {
      int t = __shfl_up(incl, o, 64);
      if (l >= o) incl += t;
    }
    if (l < NB) boffs[l] = incl - v;
  }
  __syncthreads();
  const int lane = threadIdx.x & 63, wid = threadIdx.x >> 6;
  const int slot = lane >> 4, sub = lane & 15;
  float4 LWreg[16];  // LW[slot*16+kl][4*sub..4*sub+3]
#pragma unroll
  for (int kl = 0; kl < 16; ++kl)
    LWreg[kl] = reinterpret_cast<const float4*>(LW)[(slot * 16 + kl) * 16 + sub];
  const int r = blockIdx.x * 4 + wid;  // grid exact: 12500*4 = 50000
  const int cnt = deg[r];
  const int2* pp = pairs + (boffs[r >> 10] + offL[r]);
  float4 acc = make_float4(0.f, 0.f, 0.f, 0.f);
  float wsum = 0.f;
  for (int i = 0; i < cnt; i += 16) {
    int2 p[4];
    float w[4];
#pragma unroll
    for (int j = 0; j < 4; ++j) {
      int e = i + j * 4 + slot;
      bool v = e < cnt;
      p[j] = pp[v ? e : 0];  // pp[0] valid: loop entered => cnt >= 1
      w[j] = v ? __int_as_float(p[j].y) : 0.f;
    }
#pragma unroll
    for (int j = 0; j < 4; ++j) {
      ushort4 uz = reinterpret_cast<const ushort4*>(zb)[(size_t)p[j].x * 16 + sub];
      acc.x = fmaf(w[j], __uint_as_float((unsigned)uz.x << 16), acc.x);
      acc.y = fmaf(w[j], __uint_as_float((unsigned)uz.y << 16), acc.y);
      acc.z = fmaf(w[j], __uint_as_float((unsigned)uz.z << 16), acc.z);
      acc.w = fmaf(w[j], __uint_as_float((unsigned)uz.w << 16), acc.w);
      wsum += w[j];
    }
  }
  // loop-weight partial: k in [slot*16, slot*16+16)
  float4 lacc = make_float4(0.f, 0.f, 0.f, 0.f);
#pragma unroll
  for (int j = 0; j < 4; ++j) {
    ushort4 uz = reinterpret_cast<const ushort4*>(zb)[(size_t)r * 16 + slot * 4 + j];
    float zk[4] = {__uint_as_float((unsigned)uz.x << 16),
                   __uint_as_float((unsigned)uz.y << 16),
                   __uint_as_float((unsigned)uz.z << 16),
                   __uint_as_float((unsigned)uz.w << 16)};
#pragma unroll
    for (int c = 0; c < 4; ++c) {
      float4 lw = LWreg[4 * j + c];
      lacc.x = fmaf(zk[c], lw.x, lacc.x);
      lacc.y = fmaf(zk[c], lw.y, lacc.y);
      lacc.z = fmaf(zk[c], lw.z, lacc.z);
      lacc.w = fmaf(zk[c], lw.w, lacc.w);
    }
  }
  wsum += __shfl_xor(wsum, 16, 64);
  wsum += __shfl_xor(wsum, 32, 64);
  float inv = (cnt > 0) ? 1.f / wsum : 0.f;
  float4 t;
  t.x = fmaf(acc.x, inv, lacc.x);
  t.y = fmaf(acc.y, inv, lacc.y);
  t.z = fmaf(acc.z, inv, lacc.z);
  t.w = fmaf(acc.w, inv, lacc.w);
  t.x += __shfl_xor(t.x, 16, 64); t.x += __shfl_xor(t.x, 32, 64);
  t.y += __shfl_xor(t.y, 16, 64); t.y += __shfl_xor(t.y, 32, 64);
  t.z += __shfl_xor(t.z, 16, 64); t.z += __shfl_xor(t.z, 32, 64);
  t.w += __shfl_xor(t.w, 16, 64); t.w += __shfl_xor(t.w, 32, 64);
  if (slot == 0) {
    float4 res;
    res.x = (cnt > 0 && t.x > 0.f) ? t.x : 0.f;
    res.y = (cnt > 0 && t.y > 0.f) ? t.y : 0.f;
    res.z = (cnt > 0 && t.z > 0.f) ? t.z : 0.f;
    res.w = (cnt > 0 && t.w > 0.f) ? t.w : 0.f;
    reinterpret_cast<float4*>(out)[(size_t)r * 16 + sub] = res;
  }
}

extern "C" void kernel_launch(void* const* d_in, const int* in_sizes, int n_in,
                              void* d_out, int out_size, void* d_ws, size_t ws_size,
                              hipStream_t stream) {
  const float* h    = (const float*)d_in[0];  // [N,128]
  const float* r_h  = (const float*)d_in[1];  // [E,64]
  const float* W_fc = (const float*)d_in[2];  // [64,128]
  const float* attn = (const float*)d_in[3];  // [1,192]
  const float* LW   = (const float*)d_in[4];  // [64,64]
  const int* esrc   = (const int*)d_in[5];    // [E]
  const int* edst   = (const int*)d_in[6];    // [E]
  float* out = (float*)d_out;                 // [N,64]

  char* ws = (char*)d_ws;
  __hip_bfloat16* zb = (__hip_bfloat16*)(ws);  //  6,400,000 B
  int2*  pairs = (int2*)(ws + 6400000);        //  6,400,000 B
  int*   rank  = (int*)(ws + 12800000);        //  3,200,000 B
  float* d3    = (float*)(ws + 16000000);      //  3,200,000 B
  float* s1    = (float*)(ws + 19200000);      //    200,000 B
  float* s2    = (float*)(ws + 19400000);      //    200,000 B
  int*   deg   = (int*)(ws + 19600000);        //    200,000 B
  int*   offL  = (int*)(ws + 19800000);        //    200,000 B
  int*   bsum  = (int*)(ws + 20000000);        //        256 B
  // total ws use ~20 MB

  hipMemsetAsync(deg, 0, (size_t)NN * sizeof(int), stream);

  k_front<<<PA_BLOCKS + DEG_BLOCKS + RH_BLOCKS, 256, 0, stream>>>(
      h, W_fc, attn, edst, r_h, zb, s1, s2, deg, rank, d3);
  k_scan1<<<NB, 1024, 0, stream>>>(deg, offL, bsum);
  k_scatter<<<(EE / 4 + 255) / 256, 256, 0, stream>>>(
      esrc, edst, d3, s1, s2, rank, offL, bsum, pairs);
  k_agg<<<NN / 4, 256, 0, stream>>>(zb, pairs, offL, bsum, deg, LW, out);
}

// Round 5
// 397.362 us; speedup vs baseline: 1.1281x; 1.0686x over previous
//
#include <hip/hip_runtime.h>
#include <hip/hip_bf16.h>

#define NN 50000
#define EE 800000
#define IND 128
#define OUTD 64
#define NB 49           // ceil(NN/1024) scan blocks
#define PA_BLOCKS 782   // ceil(NN/64) GEMM blocks
#define DEG_BLOCKS 391  // ceil(EE/2048) deg blocks
#define RH_BLOCKS 6250  // EE*16/2048 r_h-stream blocks (8 float4 per thread)

// ---------------- Front (fused, 3 block ranges) ----------------------------
// [0,782):        z = h@W_fc^T via LDS-tiled fp32 GEMM (R4 post-mortem: the
//                 readlane+Wreg[128] design NEVER got registers — VGPR=84
//                 with spills through 3 attempts; this structure needs ~48).
// [782,1173):     deg/rank: rank[e] = atomicAdd(&deg[edst[e]],1)
// [1173,7423):    d3[e] = r_h[e]·w3 (204.8 MB logical, ~114 MB HBM stream)
// LDS now 8.7 KB (was 33) -> 8 blocks/CU for all branches.
__global__ __launch_bounds__(256) void k_front(
    const float* __restrict__ h, const float* __restrict__ W,
    const float* __restrict__ attn, const int* __restrict__ edst,
    const float* __restrict__ r_h,
    __hip_bfloat16* __restrict__ zb, float* __restrict__ s1,
    float* __restrict__ s2, int* __restrict__ deg, int* __restrict__ rank,
    float* __restrict__ d3) {
  __shared__ float sA[16][68];  // sA[k][row] = h[base+row][k0+k]; 68%32==4 ->
  __shared__ float sB[16][68];  // 2-way store conflict only (free, m136)
  const int tid = threadIdx.x;
  if (blockIdx.x >= PA_BLOCKS + DEG_BLOCKS) {  // ---- r_h·w3 stream
    const int base4 = (blockIdx.x - (PA_BLOCKS + DEG_BLOCKS)) * 2048 + tid;
    const int sub = tid & 15;
    const float4 wv = reinterpret_cast<const float4*>(attn + 2 * OUTD)[sub];
    float4 rv[8];
#pragma unroll
    for (int j = 0; j < 8; ++j)
      rv[j] = reinterpret_cast<const float4*>(r_h)[base4 + j * 256];
    float d[8];
#pragma unroll
    for (int j = 0; j < 8; ++j)
      d[j] = rv[j].x * wv.x + rv[j].y * wv.y + rv[j].z * wv.z + rv[j].w * wv.w;
#pragma unroll
    for (int m = 1; m <= 8; m <<= 1) {
#pragma unroll
      for (int j = 0; j < 8; ++j) d[j] += __shfl_xor(d[j], m, 64);
    }
    if (sub == 0) {
      const int row0 = base4 >> 4;
#pragma unroll
      for (int j = 0; j < 8; ++j) d3[row0 + 16 * j] = d[j];
    }
    return;
  }
  if (blockIdx.x >= PA_BLOCKS) {  // ---- deg/rank
    const int base = (blockIdx.x - PA_BLOCKS) * 2048 + tid;
#pragma unroll
    for (int j = 0; j < 8; ++j) {
      int e = base + j * 256;
      if (e < EE) rank[e] = atomicAdd(&deg[edst[e]], 1);
    }
    return;
  }
  // ---- GEMM: block = 64 rows x 64 cols, thread tile 4x4, K chunks of 16.
  const int base = blockIdx.x * 64;
  const int lrow = tid >> 2;         // loader: row/col 0..63
  const int lk4 = (tid & 3) * 4;     // loader: k offset 0,4,8,12
  const int tr = tid >> 4;           // compute: rows tr*4..+3
  const int tc = tid & 15;           // compute: cols tc*4..+3
  int grow = base + lrow;
  if (grow >= NN) grow = NN - 1;     // tail clamp (loads only; stores guarded)
  const float* hrow = h + (size_t)grow * IND;
  const float* wrow = W + lrow * IND;
  float acc[4][4] = {};
  for (int c = 0; c < 8; ++c) {
    const int k0 = c * 16;
    const float4 av = *reinterpret_cast<const float4*>(hrow + k0 + lk4);
    const float4 bv = *reinterpret_cast<const float4*>(wrow + k0 + lk4);
    sA[lk4 + 0][lrow] = av.x; sA[lk4 + 1][lrow] = av.y;
    sA[lk4 + 2][lrow] = av.z; sA[lk4 + 3][lrow] = av.w;
    sB[lk4 + 0][lrow] = bv.x; sB[lk4 + 1][lrow] = bv.y;
    sB[lk4 + 2][lrow] = bv.z; sB[lk4 + 3][lrow] = bv.w;
    __syncthreads();
#pragma unroll
    for (int k = 0; k < 16; ++k) {
      const float4 a = *reinterpret_cast<const float4*>(&sA[k][tr * 4]);
      const float4 b = *reinterpret_cast<const float4*>(&sB[k][tc * 4]);
      acc[0][0] = fmaf(a.x, b.x, acc[0][0]); acc[0][1] = fmaf(a.x, b.y, acc[0][1]);
      acc[0][2] = fmaf(a.x, b.z, acc[0][2]); acc[0][3] = fmaf(a.x, b.w, acc[0][3]);
      acc[1][0] = fmaf(a.y, b.x, acc[1][0]); acc[1][1] = fmaf(a.y, b.y, acc[1][1]);
      acc[1][2] = fmaf(a.y, b.z, acc[1][2]); acc[1][3] = fmaf(a.y, b.w, acc[1][3]);
      acc[2][0] = fmaf(a.z, b.x, acc[2][0]); acc[2][1] = fmaf(a.z, b.y, acc[2][1]);
      acc[2][2] = fmaf(a.z, b.z, acc[2][2]); acc[2][3] = fmaf(a.z, b.w, acc[2][3]);
      acc[3][0] = fmaf(a.w, b.x, acc[3][0]); acc[3][1] = fmaf(a.w, b.y, acc[3][1]);
      acc[3][2] = fmaf(a.w, b.z, acc[3][2]); acc[3][3] = fmaf(a.w, b.w, acc[3][3]);
    }
    __syncthreads();
  }
  // Epilogue: zb (bf16), s1 = z.w1, s2 = z.w2. Row r is owned by the 16
  // lanes tc=0..15 (tid = tr*16+tc, aligned 16-lane group -> shfl_xor 1..8).
  const float4 w1v = *reinterpret_cast<const float4*>(attn + tc * 4);
  const float4 w2v = *reinterpret_cast<const float4*>(attn + OUTD + tc * 4);
#pragma unroll
  for (int i = 0; i < 4; ++i) {
    const int r = base + tr * 4 + i;
    const bool valid = r < NN;
    const float zx = acc[i][0], zy = acc[i][1], zz = acc[i][2], zw = acc[i][3];
    float p = zx * w1v.x + zy * w1v.y + zz * w1v.z + zw * w1v.w;
    float q = zx * w2v.x + zy * w2v.y + zz * w2v.z + zw * w2v.w;
#pragma unroll
    for (int m = 1; m <= 8; m <<= 1) {
      p += __shfl_xor(p, m, 64);
      q += __shfl_xor(q, m, 64);
    }
    if (valid) {
      __hip_bfloat16 b0 = __float2bfloat16(zx), b1 = __float2bfloat16(zy);
      __hip_bfloat16 b2 = __float2bfloat16(zz), b3 = __float2bfloat16(zw);
      ushort4 u;
      u.x = reinterpret_cast<unsigned short&>(b0);
      u.y = reinterpret_cast<unsigned short&>(b1);
      u.z = reinterpret_cast<unsigned short&>(b2);
      u.w = reinterpret_cast<unsigned short&>(b3);
      reinterpret_cast<ushort4*>(zb)[(size_t)r * 16 + tc] = u;
      if (tc == 0) { s1[r] = p; s2[r] = q; }
    }
  }
}

// ---------------- Scan: exclusive prefix over deg (CSR offsets) ------------
// Per-1024 block local offsets + per-block sums; the 49-entry block-level
// prefix is recomputed inline by consumers (no k_scan2 dispatch).
__global__ __launch_bounds__(1024) void k_scan1(
    const int* __restrict__ deg, int* __restrict__ offL,
    int* __restrict__ blocksum) {
  __shared__ int wsum[16];
  __shared__ int woff[17];
  const int tid = threadIdx.x;
  const int gid = blockIdx.x * 1024 + tid;
  const int lane = tid & 63, wid = tid >> 6;
  int v = (gid < NN) ? deg[gid] : 0;
  int incl = v;
#pragma unroll
  for (int o = 1; o < 64; o <<= 1) {
    int t = __shfl_up(incl, o, 64);
    if (lane >= o) incl += t;
  }
  if (lane == 63) wsum[wid] = incl;
  __syncthreads();
  if (wid == 0 && lane < 16) {
    int s = wsum[lane];
    int si = s;
#pragma unroll
    for (int o = 1; o < 16; o <<= 1) {
      int t = __shfl_up(si, o, 64);
      if (lane >= o) si += t;
    }
    woff[lane] = si - s;
    if (lane == 15) woff[16] = si;
  }
  __syncthreads();
  if (gid < NN) offL[gid] = woff[wid] + incl - v;
  if (tid == 0) blocksum[blockIdx.x] = woff[16];
}

// ---------------- Scatter: 4 edges/thread, vector edge loads ---------------
// ee = exp(leaky(s1[src]+s2[dst]+d3[e])); pairs[off[dst]+rank[e]] = (src,ee).
// First wave computes the 49-entry block-offset prefix into LDS. 4 edges/
// thread: int4/float4 coalesced stream loads, 12 random L2-hot gathers in
// flight. No seg_max: |a| small, exp safe in f32; alpha identical.
__global__ __launch_bounds__(256) void k_scatter(
    const int* __restrict__ esrc, const int* __restrict__ edst,
    const float* __restrict__ d3, const float* __restrict__ s1,
    const float* __restrict__ s2, const int* __restrict__ rank,
    const int* __restrict__ offL, const int* __restrict__ bsum,
    int2* __restrict__ pairs) {
  __shared__ int boffs[NB];
  if (threadIdx.x < 64) {
    int l = threadIdx.x;
    int v = (l < NB) ? bsum[l] : 0;
    int incl = v;
#pragma unroll
    for (int o = 1; o < 64; o <<= 1) {
      int t = __shfl_up(incl, o, 64);
      if (l >= o) incl += t;
    }
    if (l < NB) boffs[l] = incl - v;
  }
  __syncthreads();
  const int t = blockIdx.x * 256 + threadIdx.x;
  if (t >= EE / 4) return;
  const int4 s4 = reinterpret_cast<const int4*>(esrc)[t];
  const int4 dd4 = reinterpret_cast<const int4*>(edst)[t];
  const float4 d34 = reinterpret_cast<const float4*>(d3)[t];
  const int4 rk4 = reinterpret_cast<const int4*>(rank)[t];
  float v1x = s1[s4.x], v1y = s1[s4.y], v1z = s1[s4.z], v1w = s1[s4.w];
  float v2x = s2[dd4.x], v2y = s2[dd4.y], v2z = s2[dd4.z], v2w = s2[dd4.w];
  int oLx = offL[dd4.x], oLy = offL[dd4.y], oLz = offL[dd4.z], oLw = offL[dd4.w];
  int bx = boffs[dd4.x >> 10], by = boffs[dd4.y >> 10];
  int bz = boffs[dd4.z >> 10], bw = boffs[dd4.w >> 10];
  float ax = v1x + v2x + d34.x, ay = v1y + v2y + d34.y;
  float az = v1z + v2z + d34.z, aw = v1w + v2w + d34.w;
  float ex = __expf(ax > 0.f ? ax : 0.01f * ax);
  float ey = __expf(ay > 0.f ? ay : 0.01f * ay);
  float ez = __expf(az > 0.f ? az : 0.01f * az);
  float ew = __expf(aw > 0.f ? aw : 0.01f * aw);
  pairs[bx + oLx + rk4.x] = make_int2(s4.x, __float_as_int(ex));
  pairs[by + oLy + rk4.y] = make_int2(s4.y, __float_as_int(ey));
  pairs[bz + oLz + rk4.z] = make_int2(s4.z, __float_as_int(ez));
  pairs[bw + oLw + rk4.w] = make_int2(s4.w, __float_as_int(ew));
}

// ---------------- Agg: gather per dst node ---------------------------------
// One wave per node. lane = (slot = lane>>4, sub = lane&15): slot indexes
// edges, sub the channel-quad. Gathers bf16 zb rows (128 B); 16 edges per
// mega-iteration. First wave computes boffs inline.
__global__ __launch_bounds__(256) void k_agg(
    const __hip_bfloat16* __restrict__ zb, const int2* __restrict__ pairs,
    const int* __restrict__ offL, const int* __restrict__ bsum,
    const int* __restrict__ deg, const float* __restrict__ LW,
    float* __restrict__ out) {
  __shared__ int boffs[NB];
  if (threadIdx.x < 64) {
    int l = threadIdx.x;
    int v = (l < NB) ? bsum[l] : 0;
    int incl = v;
#pragma unroll
    for (int o = 1; o < 64; o <<= 1) {
      int t = __shfl_up(incl, o, 64);
      if (l >= o) incl += t;
    }
    if (l < NB) boffs[l] = incl - v;
  }
  __syncthreads();
  const int lane = threadIdx.x & 63, wid = threadIdx.x >> 6;
  const int slot = lane >> 4, sub = lane & 15;
  float4 LWreg[16];  // LW[slot*16+kl][4*sub..4*sub+3]
#pragma unroll
  for (int kl = 0; kl < 16; ++kl)
    LWreg[kl] = reinterpret_cast<const float4*>(LW)[(slot * 16 + kl) * 16 + sub];
  const int r = blockIdx.x * 4 + wid;  // grid exact: 12500*4 = 50000
  const int cnt = deg[r];
  const int2* pp = pairs + (boffs[r >> 10] + offL[r]);
  float4 acc = make_float4(0.f, 0.f, 0.f, 0.f);
  float wsum = 0.f;
  for (int i = 0; i < cnt; i += 16) {
    int2 p[4];
    float w[4];
#pragma unroll
    for (int j = 0; j < 4; ++j) {
      int e = i + j * 4 + slot;
      bool v = e < cnt;
      p[j] = pp[v ? e : 0];  // pp[0] valid: loop entered => cnt >= 1
      w[j] = v ? __int_as_float(p[j].y) : 0.f;
    }
#pragma unroll
    for (int j = 0; j < 4; ++j) {
      ushort4 uz = reinterpret_cast<const ushort4*>(zb)[(size_t)p[j].x * 16 + sub];
      acc.x = fmaf(w[j], __uint_as_float((unsigned)uz.x << 16), acc.x);
      acc.y = fmaf(w[j], __uint_as_float((unsigned)uz.y << 16), acc.y);
      acc.z = fmaf(w[j], __uint_as_float((unsigned)uz.z << 16), acc.z);
      acc.w = fmaf(w[j], __uint_as_float((unsigned)uz.w << 16), acc.w);
      wsum += w[j];
    }
  }
  // loop-weight partial: k in [slot*16, slot*16+16)
  float4 lacc = make_float4(0.f, 0.f, 0.f, 0.f);
#pragma unroll
  for (int j = 0; j < 4; ++j) {
    ushort4 uz = reinterpret_cast<const ushort4*>(zb)[(size_t)r * 16 + slot * 4 + j];
    float zk[4] = {__uint_as_float((unsigned)uz.x << 16),
                   __uint_as_float((unsigned)uz.y << 16),
                   __uint_as_float((unsigned)uz.z << 16),
                   __uint_as_float((unsigned)uz.w << 16)};
#pragma unroll
    for (int c = 0; c < 4; ++c) {
      float4 lw = LWreg[4 * j + c];
      lacc.x = fmaf(zk[c], lw.x, lacc.x);
      lacc.y = fmaf(zk[c], lw.y, lacc.y);
      lacc.z = fmaf(zk[c], lw.z, lacc.z);
      lacc.w = fmaf(zk[c], lw.w, lacc.w);
    }
  }
  wsum += __shfl_xor(wsum, 16, 64);
  wsum += __shfl_xor(wsum, 32, 64);
  float inv = (cnt > 0) ? 1.f / wsum : 0.f;
  float4 t;
  t.x = fmaf(acc.x, inv, lacc.x);
  t.y = fmaf(acc.y, inv, lacc.y);
  t.z = fmaf(acc.z, inv, lacc.z);
  t.w = fmaf(acc.w, inv, lacc.w);
  t.x += __shfl_xor(t.x, 16, 64); t.x += __shfl_xor(t.x, 32, 64);
  t.y += __shfl_xor(t.y, 16, 64); t.y += __shfl_xor(t.y, 32, 64);
  t.z += __shfl_xor(t.z, 16, 64); t.z += __shfl_xor(t.z, 32, 64);
  t.w += __shfl_xor(t.w, 16, 64); t.w += __shfl_xor(t.w, 32, 64);
  if (slot == 0) {
    float4 res;
    res.x = (cnt > 0 && t.x > 0.f) ? t.x : 0.f;
    res.y = (cnt > 0 && t.y > 0.f) ? t.y : 0.f;
    res.z = (cnt > 0 && t.z > 0.f) ? t.z : 0.f;
    res.w = (cnt > 0 && t.w > 0.f) ? t.w : 0.f;
    reinterpret_cast<float4*>(out)[(size_t)r * 16 + sub] = res;
  }
}

extern "C" void kernel_launch(void* const* d_in, const int* in_sizes, int n_in,
                              void* d_out, int out_size, void* d_ws, size_t ws_size,
                              hipStream_t stream) {
  const float* h    = (const float*)d_in[0];  // [N,128]
  const float* r_h  = (const float*)d_in[1];  // [E,64]
  const float* W_fc = (const float*)d_in[2];  // [64,128]
  const float* attn = (const float*)d_in[3];  // [1,192]
  const float* LW   = (const float*)d_in[4];  // [64,64]
  const int* esrc   = (const int*)d_in[5];    // [E]
  const int* edst   = (const int*)d_in[6];    // [E]
  float* out = (float*)d_out;                 // [N,64]

  char* ws = (char*)d_ws;
  __hip_bfloat16* zb = (__hip_bfloat16*)(ws);  //  6,400,000 B
  int2*  pairs = (int2*)(ws + 6400000);        //  6,400,000 B
  int*   rank  = (int*)(ws + 12800000);        //  3,200,000 B
  float* d3    = (float*)(ws + 16000000);      //  3,200,000 B
  float* s1    = (float*)(ws + 19200000);      //    200,000 B
  float* s2    = (float*)(ws + 19400000);      //    200,000 B
  int*   deg   = (int*)(ws + 19600000);        //    200,000 B
  int*   offL  = (int*)(ws + 19800000);        //    200,000 B
  int*   bsum  = (int*)(ws + 20000000);        //        256 B
  // total ws use ~20 MB

  hipMemsetAsync(deg, 0, (size_t)NN * sizeof(int), stream);

  k_front<<<PA_BLOCKS + DEG_BLOCKS + RH_BLOCKS, 256, 0, stream>>>(
      h, W_fc, attn, edst, r_h, zb, s1, s2, deg, rank, d3);
  k_scan1<<<NB, 1024, 0, stream>>>(deg, offL, bsum);
  k_scatter<<<(EE / 4 + 255) / 256, 256, 0, stream>>>(
      esrc, edst, d3, s1, s2, rank, offL, bsum, pairs);
  k_agg<<<NN / 4, 256, 0, stream>>>(zb, pairs, offL, bsum, deg, LW, out);
}